// Round 1
// baseline (207.220 us; speedup 1.0000x reference)
//
#include <hip/hip_runtime.h>
#include <stdint.h>

// ---------------------------------------------------------------------------
// Attention_59236188947093: x[4,8,512,512] -> qkv proj -> 8-head attn (n=512,
// d=64) -> out proj. pos_bias is a softmax-axis constant => mathematically
// irrelevant, skipped. All matmuls in bf16 MFMA (16x16x32), fp32 accum.
// ---------------------------------------------------------------------------

typedef __attribute__((ext_vector_type(8))) short bf16x8;
typedef __attribute__((ext_vector_type(4))) float f32x4;
typedef __attribute__((ext_vector_type(4))) unsigned short us4;
typedef __attribute__((ext_vector_type(4))) float float4v;

__device__ __forceinline__ unsigned short f2b(float f) {
  union { float f; uint32_t u; } x; x.f = f;
  uint32_t r = x.u + 0x7fffu + ((x.u >> 16) & 1u);
  return (unsigned short)(r >> 16);
}

__device__ __forceinline__ f32x4 mfma16(bf16x8 a, bf16x8 b, f32x4 c) {
  return __builtin_amdgcn_mfma_f32_16x16x32_bf16(a, b, c, 0, 0, 0);
}

__device__ __forceinline__ void gload_lds16(const unsigned short* g, unsigned short* l) {
  __builtin_amdgcn_global_load_lds(
      (const __attribute__((address_space(1))) unsigned int*)g,
      (__attribute__((address_space(3))) unsigned int*)l, 16, 0, 0);
}

// ---------------------------------------------------------------------------
// cast kernels
// ---------------------------------------------------------------------------
__global__ __launch_bounds__(256) void cast_x_kernel(
    const float* __restrict__ src, unsigned short* __restrict__ dst) {
  size_t i = ((size_t)blockIdx.x * 256 + threadIdx.x) * 4;
  float4v v = *(const float4v*)(src + i);
  us4 o;
#pragma unroll
  for (int j = 0; j < 4; ++j) o[j] = f2b(v[j]);
  *(us4*)(dst + i) = o;
}

// src[R][C] fp32 -> dst[C][R] bf16
__global__ __launch_bounds__(256) void transpose_cast_kernel(
    const float* __restrict__ src, unsigned short* __restrict__ dst, int R, int C) {
  __shared__ float tile[64][65];
  const int tc0 = blockIdx.x * 64;
  const int tr0 = blockIdx.y * 64;
#pragma unroll
  for (int k2 = 0; k2 < 16; ++k2) {
    int idx = threadIdx.x + k2 * 256;
    int r = idx >> 6, c = idx & 63;
    tile[r][c] = src[(size_t)(tr0 + r) * C + tc0 + c];
  }
  __syncthreads();
#pragma unroll
  for (int k2 = 0; k2 < 16; ++k2) {
    int idx = threadIdx.x + k2 * 256;
    int c = idx >> 6, r = idx & 63;
    dst[(size_t)(tc0 + c) * R + tr0 + r] = f2b(tile[r][c]);
  }
}

// ---------------------------------------------------------------------------
// GEMM core: C[128x128] tile of A[M][K] * Bt[N][K]^T, K multiple of 64.
// 4 waves in 2x2, each wave 64x64 via 4x4 frags of 16x16x32 bf16 MFMA.
// ---------------------------------------------------------------------------
__device__ __forceinline__ void gemm_core(
    const unsigned short* __restrict__ A, const unsigned short* __restrict__ Bt,
    int K, int r0, int c0, unsigned short* As, unsigned short* Bs,
    f32x4 (&acc)[4][4]) {
  const int tid = threadIdx.x;
  const int lane = tid & 63;
  const int wave = tid >> 6;
  const int wr = (wave >> 1) * 64;
  const int wc = (wave & 1) * 64;
  const int l15 = lane & 15;
  const int g = lane >> 4;

#pragma unroll
  for (int m = 0; m < 4; ++m)
#pragma unroll
    for (int n = 0; n < 4; ++n) acc[m][n] = (f32x4){0.f, 0.f, 0.f, 0.f};

  for (int kt = 0; kt < K; kt += 64) {
#pragma unroll
    for (int i = 0; i < 4; ++i) {
      int chunk = tid + i * 256;        // 1024 chunks of 16B per 128x64 tile
      int row = chunk >> 3;
      int c8 = (chunk & 7) << 3;
      gload_lds16(A + (size_t)(r0 + row) * K + kt + c8, As + chunk * 8);
      gload_lds16(Bt + (size_t)(c0 + row) * K + kt + c8, Bs + chunk * 8);
    }
    __syncthreads();
#pragma unroll
    for (int kk = 0; kk < 64; kk += 32) {
      bf16x8 af[4], bfr[4];
#pragma unroll
      for (int m = 0; m < 4; ++m)
        af[m] = *(const bf16x8*)(As + (wr + m * 16 + l15) * 64 + kk + g * 8);
#pragma unroll
      for (int n = 0; n < 4; ++n)
        bfr[n] = *(const bf16x8*)(Bs + (wc + n * 16 + l15) * 64 + kk + g * 8);
#pragma unroll
      for (int m = 0; m < 4; ++m)
#pragma unroll
        for (int n = 0; n < 4; ++n) acc[m][n] = mfma16(af[m], bfr[n], acc[m][n]);
    }
    __syncthreads();
  }
}

// ---------------------------------------------------------------------------
// QKV projection: xb[16384][512] * wqbT[1536][512]^T -> scatter q/k/vt bf16
// q,k: [bh=256][n=512][d=64]; vt: [bh][d=64][n=512]. q scaled by d^-0.5.
// ---------------------------------------------------------------------------
__global__ __launch_bounds__(256) void gemm_qkv_kernel(
    const unsigned short* __restrict__ xb, const unsigned short* __restrict__ wqbT,
    unsigned short* __restrict__ qb, unsigned short* __restrict__ kb,
    unsigned short* __restrict__ vtb) {
  __shared__ unsigned short As[8192], Bs[8192];
  f32x4 acc[4][4];
  const int r0 = blockIdx.x * 128;
  const int c0 = blockIdx.y * 128;
  gemm_core(xb, wqbT, 512, r0, c0, As, Bs, acc);

  const int tid = threadIdx.x, lane = tid & 63, wave = tid >> 6;
  const int wr = (wave >> 1) * 64, wc = (wave & 1) * 64;
  const int l15 = lane & 15, g = lane >> 4;
  const int part = c0 >> 9;  // 128-wide tile lies in exactly one of q/k/v

#pragma unroll
  for (int n = 0; n < 4; ++n) {
    int e = c0 + wc + n * 16 + l15;
    int rem = e & 511;
    int h = rem >> 6, d = rem & 63;
#pragma unroll
    for (int m = 0; m < 4; ++m) {
      int i0g = r0 + wr + m * 16 + 4 * g;  // global rows i0g..i0g+3
      int bm = i0g >> 9;
      int i = i0g & 511;
      int bh = bm * 8 + h;
      if (part == 0) {
        unsigned short* p = qb + ((size_t)bh * 512 + i) * 64 + d;
#pragma unroll
        for (int rr = 0; rr < 4; ++rr) p[(size_t)rr * 64] = f2b(acc[m][n][rr] * 0.125f);
      } else if (part == 1) {
        unsigned short* p = kb + ((size_t)bh * 512 + i) * 64 + d;
#pragma unroll
        for (int rr = 0; rr < 4; ++rr) p[(size_t)rr * 64] = f2b(acc[m][n][rr]);
      } else {
        us4 v;
#pragma unroll
        for (int rr = 0; rr < 4; ++rr) v[rr] = f2b(acc[m][n][rr]);
        *(us4*)(vtb + ((size_t)bh * 64 + d) * 512 + i) = v;
      }
    }
  }
}

// ---------------------------------------------------------------------------
// Output projection: ao[16384][512] * wobT[512][512]^T -> d_out fp32
// ---------------------------------------------------------------------------
__global__ __launch_bounds__(256) void gemm_out_kernel(
    const unsigned short* __restrict__ ao, const unsigned short* __restrict__ wobT,
    float* __restrict__ out) {
  __shared__ unsigned short As[8192], Bs[8192];
  f32x4 acc[4][4];
  const int r0 = blockIdx.x * 128;
  const int c0 = blockIdx.y * 128;
  gemm_core(ao, wobT, 512, r0, c0, As, Bs, acc);

  const int tid = threadIdx.x, lane = tid & 63, wave = tid >> 6;
  const int wr = (wave >> 1) * 64, wc = (wave & 1) * 64;
  const int l15 = lane & 15, g = lane >> 4;
#pragma unroll
  for (int m = 0; m < 4; ++m) {
    int i0g = r0 + wr + m * 16 + 4 * g;
#pragma unroll
    for (int n = 0; n < 4; ++n) {
      int e = c0 + wc + n * 16 + l15;
#pragma unroll
      for (int rr = 0; rr < 4; ++rr)
        out[(size_t)(i0g + rr) * 512 + e] = acc[m][n][rr];
    }
  }
}

// ---------------------------------------------------------------------------
// Fused attention: one block = (bh, 64 q-rows); 4 waves x 16 q-rows each.
// sim (16x512 fp32) entirely in registers; wave-parallel softmax; P->PV
// via tiny per-wave LDS transpose scratch. out^T = mfma(A=V^T, B=P^T).
// ---------------------------------------------------------------------------
__global__ __launch_bounds__(256, 2) void attn_kernel(
    const unsigned short* __restrict__ qb, const unsigned short* __restrict__ kb,
    const unsigned short* __restrict__ vtb, unsigned short* __restrict__ ao) {
  __shared__ unsigned short Ps[4][16][40];
  const int bh = blockIdx.y;
  const int qt = blockIdx.x;
  const int tid = threadIdx.x, lane = tid & 63, wave = tid >> 6;
  const int l15 = lane & 15, g = lane >> 4;
  const int qrow0 = qt * 64 + wave * 16;

  const unsigned short* Q = qb + ((size_t)bh * 512 + qrow0) * 64;
  const unsigned short* Kp = kb + (size_t)bh * 512 * 64;
  const unsigned short* Vt = vtb + (size_t)bh * 64 * 512;

  bf16x8 qf0 = *(const bf16x8*)(Q + l15 * 64 + g * 8);
  bf16x8 qf1 = *(const bf16x8*)(Q + l15 * 64 + 32 + g * 8);

  // QK^T: sim[t] holds rows (4g+rr), cols (16t + l15)
  f32x4 sim[32];
#pragma unroll
  for (int t = 0; t < 32; ++t) {
    const unsigned short* Kt = Kp + (size_t)(t * 16 + l15) * 64 + g * 8;
    bf16x8 b0 = *(const bf16x8*)(Kt);
    bf16x8 b1 = *(const bf16x8*)(Kt + 32);
    f32x4 c = (f32x4){0.f, 0.f, 0.f, 0.f};
    c = mfma16(qf0, b0, c);
    c = mfma16(qf1, b1, c);
    sim[t] = c;
  }

  // softmax per row: row (4g+rr) lives in one 16-lane group across 32 regs
#pragma unroll
  for (int rr = 0; rr < 4; ++rr) {
    float mx = -3.0e38f;
#pragma unroll
    for (int t = 0; t < 32; ++t) mx = fmaxf(mx, sim[t][rr]);
#pragma unroll
    for (int o = 1; o < 16; o <<= 1) mx = fmaxf(mx, __shfl_xor(mx, o));
    float s = 0.f;
#pragma unroll
    for (int t = 0; t < 32; ++t) {
      float e = __expf(sim[t][rr] - mx);
      sim[t][rr] = e;
      s += e;
    }
#pragma unroll
    for (int o = 1; o < 16; o <<= 1) s += __shfl_xor(s, o);
    float inv = 1.f / s;
#pragma unroll
    for (int t = 0; t < 32; ++t) sim[t][rr] *= inv;
  }

  // PV: out^T[d][q] accumulated as 4 frags (d in 4x16), q = 16 cols
  f32x4 oacc[4];
#pragma unroll
  for (int m = 0; m < 4; ++m) oacc[m] = (f32x4){0.f, 0.f, 0.f, 0.f};

#pragma unroll
  for (int cch = 0; cch < 16; ++cch) {  // kv chunk of 32
#pragma unroll
    for (int p = 0; p < 2; ++p)
#pragma unroll
      for (int rr = 0; rr < 4; ++rr)
        Ps[wave][4 * g + rr][p * 16 + l15] = f2b(sim[2 * cch + p][rr]);
    asm volatile("s_waitcnt lgkmcnt(0)" ::: "memory");
    bf16x8 pf = *(const bf16x8*)(&Ps[wave][l15][g * 8]);
#pragma unroll
    for (int m = 0; m < 4; ++m) {
      bf16x8 vf = *(const bf16x8*)(Vt + (size_t)(m * 16 + l15) * 512 + cch * 32 + g * 8);
      oacc[m] = mfma16(vf, pf, oacc[m]);
    }
  }

  // store: ao[bm*512 + q][h*64 + d], d = m*16 + 4g + rr (4 bf16 packed)
  const int hh = bh & 7, bm = bh >> 3;
  unsigned short* aorow = ao + ((size_t)bm * 512 + qrow0 + l15) * 512 + hh * 64;
#pragma unroll
  for (int m = 0; m < 4; ++m) {
    us4 v;
#pragma unroll
    for (int rr = 0; rr < 4; ++rr) v[rr] = f2b(oacc[m][rr]);
    *(us4*)(aorow + m * 16 + 4 * g) = v;
  }
}

// ---------------------------------------------------------------------------
extern "C" void kernel_launch(void* const* d_in, const int* in_sizes, int n_in,
                              void* d_out, int out_size, void* d_ws, size_t ws_size,
                              hipStream_t stream) {
  const float* x = (const float*)d_in[0];
  // d_in[1] = pos_bias: mathematically a no-op (constant along softmax axis)
  const float* w_qkv = (const float*)d_in[2];
  const float* w_out = (const float*)d_in[3];
  float* out = (float*)d_out;

  char* ws = (char*)d_ws;
  const size_t SZ_XB = 16384ull * 512 * 2;        // 16.78 MB
  const size_t SZ_WQ = 1536ull * 512 * 2;         // 1.57 MB
  const size_t SZ_WO = 512ull * 512 * 2;          // 0.52 MB
  const size_t SZ_HB = 256ull * 512 * 64 * 2;     // 16.78 MB each
  unsigned short* xb = (unsigned short*)(ws);
  unsigned short* wqbT = (unsigned short*)(ws + SZ_XB);
  unsigned short* wobT = (unsigned short*)(ws + SZ_XB + SZ_WQ);
  unsigned short* qb = (unsigned short*)(ws + SZ_XB + SZ_WQ + SZ_WO);
  unsigned short* kb = (unsigned short*)(ws + SZ_XB + SZ_WQ + SZ_WO + SZ_HB);
  unsigned short* vtb = (unsigned short*)(ws + SZ_XB + SZ_WQ + SZ_WO + 2 * SZ_HB);
  unsigned short* ao = (unsigned short*)(ws + SZ_XB + SZ_WQ + SZ_WO + 3 * SZ_HB);

  cast_x_kernel<<<8192, 256, 0, stream>>>(x, xb);
  transpose_cast_kernel<<<dim3(1536 / 64, 512 / 64), 256, 0, stream>>>(w_qkv, wqbT, 512, 1536);
  transpose_cast_kernel<<<dim3(512 / 64, 512 / 64), 256, 0, stream>>>(w_out, wobT, 512, 512);
  gemm_qkv_kernel<<<dim3(128, 12), 256, 0, stream>>>(xb, wqbT, qb, kb, vtb);
  attn_kernel<<<dim3(8, 256), 256, 0, stream>>>(qb, kb, vtb, ao);
  gemm_out_kernel<<<dim3(128, 4), 256, 0, stream>>>(ao, wobT, out);
}

// Round 2
// 130.707 us; speedup vs baseline: 1.5854x; 1.5854x over previous
//
#include <hip/hip_runtime.h>
#include <stdint.h>

// ---------------------------------------------------------------------------
// Attention_59236188947093: x[4,8,512,512] -> qkv proj -> 8-head attn (n=512,
// d=64) -> out proj. pos_bias is a softmax-axis constant => mathematically
// irrelevant, skipped. All matmuls in bf16 MFMA (16x16x32), fp32 accum.
// ---------------------------------------------------------------------------

typedef __attribute__((ext_vector_type(8))) short bf16x8;
typedef __attribute__((ext_vector_type(4))) float f32x4;
typedef __attribute__((ext_vector_type(4))) unsigned short us4;
typedef __attribute__((ext_vector_type(4))) float float4v;

__device__ __forceinline__ unsigned short f2b(float f) {
  union { float f; uint32_t u; } x; x.f = f;
  uint32_t r = x.u + 0x7fffu + ((x.u >> 16) & 1u);
  return (unsigned short)(r >> 16);
}

__device__ __forceinline__ f32x4 mfma16(bf16x8 a, bf16x8 b, f32x4 c) {
  return __builtin_amdgcn_mfma_f32_16x16x32_bf16(a, b, c, 0, 0, 0);
}

__device__ __forceinline__ void gload_lds16(const unsigned short* g, unsigned short* l) {
  __builtin_amdgcn_global_load_lds(
      (const __attribute__((address_space(1))) unsigned int*)g,
      (__attribute__((address_space(3))) unsigned int*)l, 16, 0, 0);
}

// ---------------------------------------------------------------------------
// cast kernels
// ---------------------------------------------------------------------------
__global__ __launch_bounds__(256) void cast_x_kernel(
    const float* __restrict__ src, unsigned short* __restrict__ dst) {
  size_t i = ((size_t)blockIdx.x * 256 + threadIdx.x) * 4;
  float4v v = *(const float4v*)(src + i);
  us4 o;
#pragma unroll
  for (int j = 0; j < 4; ++j) o[j] = f2b(v[j]);
  *(us4*)(dst + i) = o;
}

// src[R][C] fp32 -> dst[C][R] bf16
__global__ __launch_bounds__(256) void transpose_cast_kernel(
    const float* __restrict__ src, unsigned short* __restrict__ dst, int R, int C) {
  __shared__ float tile[64][65];
  const int tc0 = blockIdx.x * 64;
  const int tr0 = blockIdx.y * 64;
#pragma unroll
  for (int k2 = 0; k2 < 16; ++k2) {
    int idx = threadIdx.x + k2 * 256;
    int r = idx >> 6, c = idx & 63;
    tile[r][c] = src[(size_t)(tr0 + r) * C + tc0 + c];
  }
  __syncthreads();
#pragma unroll
  for (int k2 = 0; k2 < 16; ++k2) {
    int idx = threadIdx.x + k2 * 256;
    int c = idx >> 6, r = idx & 63;
    dst[(size_t)(tc0 + c) * R + tr0 + r] = f2b(tile[r][c]);
  }
}

// ---------------------------------------------------------------------------
// GEMM core: C[128x128] tile of A[M][K] * Bt[N][K]^T, K multiple of 64.
// 4 waves in 2x2, each wave 64x64 via 4x4 frags of 16x16x32 bf16 MFMA.
// ---------------------------------------------------------------------------
__device__ __forceinline__ void gemm_core(
    const unsigned short* __restrict__ A, const unsigned short* __restrict__ Bt,
    int K, int r0, int c0, unsigned short* As, unsigned short* Bs,
    f32x4 (&acc)[4][4]) {
  const int tid = threadIdx.x;
  const int lane = tid & 63;
  const int wave = tid >> 6;
  const int wr = (wave >> 1) * 64;
  const int wc = (wave & 1) * 64;
  const int l15 = lane & 15;
  const int g = lane >> 4;

#pragma unroll
  for (int m = 0; m < 4; ++m)
#pragma unroll
    for (int n = 0; n < 4; ++n) acc[m][n] = (f32x4){0.f, 0.f, 0.f, 0.f};

  for (int kt = 0; kt < K; kt += 64) {
#pragma unroll
    for (int i = 0; i < 4; ++i) {
      int chunk = tid + i * 256;        // 1024 chunks of 16B per 128x64 tile
      int row = chunk >> 3;
      int c8 = (chunk & 7) << 3;
      gload_lds16(A + (size_t)(r0 + row) * K + kt + c8, As + chunk * 8);
      gload_lds16(Bt + (size_t)(c0 + row) * K + kt + c8, Bs + chunk * 8);
    }
    __syncthreads();
#pragma unroll
    for (int kk = 0; kk < 64; kk += 32) {
      bf16x8 af[4], bfr[4];
#pragma unroll
      for (int m = 0; m < 4; ++m)
        af[m] = *(const bf16x8*)(As + (wr + m * 16 + l15) * 64 + kk + g * 8);
#pragma unroll
      for (int n = 0; n < 4; ++n)
        bfr[n] = *(const bf16x8*)(Bs + (wc + n * 16 + l15) * 64 + kk + g * 8);
#pragma unroll
      for (int m = 0; m < 4; ++m)
#pragma unroll
        for (int n = 0; n < 4; ++n) acc[m][n] = mfma16(af[m], bfr[n], acc[m][n]);
    }
    __syncthreads();
  }
}

// ---------------------------------------------------------------------------
// QKV projection: xb[16384][512] * wqbT[1536][512]^T -> scatter q/k/vt bf16
// q,k: [bh=256][n=512][d=64]; vt: [bh][d=64][n=512]. q scaled by d^-0.5.
// ---------------------------------------------------------------------------
__global__ __launch_bounds__(256) void gemm_qkv_kernel(
    const unsigned short* __restrict__ xb, const unsigned short* __restrict__ wqbT,
    unsigned short* __restrict__ qb, unsigned short* __restrict__ kb,
    unsigned short* __restrict__ vtb) {
  __shared__ unsigned short As[8192], Bs[8192];
  f32x4 acc[4][4];
  const int r0 = blockIdx.x * 128;
  const int c0 = blockIdx.y * 128;
  gemm_core(xb, wqbT, 512, r0, c0, As, Bs, acc);

  const int tid = threadIdx.x, lane = tid & 63, wave = tid >> 6;
  const int wr = (wave >> 1) * 64, wc = (wave & 1) * 64;
  const int l15 = lane & 15, g = lane >> 4;
  const int part = c0 >> 9;  // 128-wide tile lies in exactly one of q/k/v

#pragma unroll
  for (int n = 0; n < 4; ++n) {
    int e = c0 + wc + n * 16 + l15;
    int rem = e & 511;
    int h = rem >> 6, d = rem & 63;
#pragma unroll
    for (int m = 0; m < 4; ++m) {
      int i0g = r0 + wr + m * 16 + 4 * g;  // global rows i0g..i0g+3
      int bm = i0g >> 9;
      int i = i0g & 511;
      int bh = bm * 8 + h;
      if (part == 0) {
        unsigned short* p = qb + ((size_t)bh * 512 + i) * 64 + d;
#pragma unroll
        for (int rr = 0; rr < 4; ++rr) p[(size_t)rr * 64] = f2b(acc[m][n][rr] * 0.125f);
      } else if (part == 1) {
        unsigned short* p = kb + ((size_t)bh * 512 + i) * 64 + d;
#pragma unroll
        for (int rr = 0; rr < 4; ++rr) p[(size_t)rr * 64] = f2b(acc[m][n][rr]);
      } else {
        us4 v;
#pragma unroll
        for (int rr = 0; rr < 4; ++rr) v[rr] = f2b(acc[m][n][rr]);
        *(us4*)(vtb + ((size_t)bh * 64 + d) * 512 + i) = v;
      }
    }
  }
}

// ---------------------------------------------------------------------------
// Output projection: ao[16384][512] * wobT[512][512]^T -> d_out fp32
// ---------------------------------------------------------------------------
__global__ __launch_bounds__(256) void gemm_out_kernel(
    const unsigned short* __restrict__ ao, const unsigned short* __restrict__ wobT,
    float* __restrict__ out) {
  __shared__ unsigned short As[8192], Bs[8192];
  f32x4 acc[4][4];
  const int r0 = blockIdx.x * 128;
  const int c0 = blockIdx.y * 128;
  gemm_core(ao, wobT, 512, r0, c0, As, Bs, acc);

  const int tid = threadIdx.x, lane = tid & 63, wave = tid >> 6;
  const int wr = (wave >> 1) * 64, wc = (wave & 1) * 64;
  const int l15 = lane & 15, g = lane >> 4;
#pragma unroll
  for (int m = 0; m < 4; ++m) {
    int i0g = r0 + wr + m * 16 + 4 * g;
#pragma unroll
    for (int n = 0; n < 4; ++n) {
      int e = c0 + wc + n * 16 + l15;
#pragma unroll
      for (int rr = 0; rr < 4; ++rr)
        out[(size_t)(i0g + rr) * 512 + e] = acc[m][n][rr];
    }
  }
}

// ---------------------------------------------------------------------------
// Fused attention v2: block = (bh, 64 q-rows), 4 waves x 16 q-rows.
// K and V^T staged through double-buffered 16KB LDS tiles via global_load_lds
// with XOR-swizzled GLOBAL source (LDS dest must stay linear), so ds_read_b128
// fragment reads are bank-balanced. sim (16x512 fp32) fully in registers.
// Pipeline: [syncthreads (drains vmcnt) | issue next tile | compute this tile].
// Tiles 0..3 = K 128-row tiles, 4..7 = V^T 128-col tiles. Softmax overlaps
// V-tile staging.
// ---------------------------------------------------------------------------
__global__ __launch_bounds__(256, 2) void attn_kernel(
    const unsigned short* __restrict__ qb, const unsigned short* __restrict__ kb,
    const unsigned short* __restrict__ vtb, unsigned short* __restrict__ ao) {
  __shared__ unsigned short kvbuf[2][8192];   // 2 x 16KB
  __shared__ unsigned short Ps[4][16][40];
  const int bh = blockIdx.x;   // x = bh so all 8 q-tiles of a bh land on one XCD stream
  const int qt = blockIdx.y;
  const int tid = threadIdx.x, lane = tid & 63, wave = tid >> 6;
  const int l15 = lane & 15, g = lane >> 4;
  const int qrow0 = qt * 64 + wave * 16;

  const unsigned short* Q = qb + ((size_t)bh * 512 + qrow0) * 64;
  const unsigned short* Kp = kb + (size_t)bh * 512 * 64;
  const unsigned short* Vt = vtb + (size_t)bh * 64 * 512;

  bf16x8 qf0 = *(const bf16x8*)(Q + l15 * 64 + g * 8);
  bf16x8 qf1 = *(const bf16x8*)(Q + l15 * 64 + 32 + g * 8);

  // staging geometry (per thread, constant across the 4 chunks it loads)
  const int krow_b = tid >> 3;                    // K: base row, +32 per i
  const int kck = (tid & 7) ^ (krow_b & 7);       // K: swizzled global chunk
  const int vrow_b = tid >> 4;                    // V: base row (d), +16 per i
  const int vck = (tid & 15) ^ (vrow_b & 15);     // V: swizzled global chunk

  f32x4 sim[32];
#pragma unroll
  for (int t = 0; t < 32; ++t) sim[t] = (f32x4){0.f, 0.f, 0.f, 0.f};

  // prologue: stage K tile 0 into buf 0
#pragma unroll
  for (int i = 0; i < 4; ++i)
    gload_lds16(Kp + (size_t)(krow_b + i * 32) * 64 + kck * 8,
                kvbuf[0] + tid * 8 + i * 2048);

  // ---- K phases: QK^T ----
#pragma unroll
  for (int kt = 0; kt < 4; ++kt) {
    __syncthreads();  // implicit vmcnt(0): tile kt landed; prev buffer free
    if (kt < 3) {
#pragma unroll
      for (int i = 0; i < 4; ++i)
        gload_lds16(Kp + (size_t)((kt + 1) * 128 + krow_b + i * 32) * 64 + kck * 8,
                    kvbuf[(kt + 1) & 1] + tid * 8 + i * 2048);
    } else {
#pragma unroll
      for (int i = 0; i < 4; ++i)
        gload_lds16(Vt + (size_t)(vrow_b + i * 16) * 512 + vck * 8,
                    kvbuf[0] + tid * 8 + i * 2048);
    }
    const unsigned short* buf = kvbuf[kt & 1];
#pragma unroll
    for (int tt = 0; tt < 8; ++tt) {
      int row = tt * 16 + l15;
      int c0 = g ^ (l15 & 7);
      bf16x8 b0 = *(const bf16x8*)(buf + (row * 8 + c0) * 8);
      bf16x8 b1 = *(const bf16x8*)(buf + (row * 8 + (c0 ^ 4)) * 8);
      sim[kt * 8 + tt] = mfma16(qf0, b0, sim[kt * 8 + tt]);
      sim[kt * 8 + tt] = mfma16(qf1, b1, sim[kt * 8 + tt]);
    }
  }

  f32x4 oacc[4];
#pragma unroll
  for (int m = 0; m < 4; ++m) oacc[m] = (f32x4){0.f, 0.f, 0.f, 0.f};

  // ---- V phases: softmax (vt==0) + PV ----
#pragma unroll
  for (int vt = 0; vt < 4; ++vt) {
    __syncthreads();  // V tile vt landed
    if (vt < 3) {
#pragma unroll
      for (int i = 0; i < 4; ++i)
        gload_lds16(Vt + (size_t)(vrow_b + i * 16) * 512 + (vt + 1) * 128 + vck * 8,
                    kvbuf[(vt + 1) & 1] + tid * 8 + i * 2048);
    }
    if (vt == 0) {
      // softmax: row (4g+rr) lives in one 16-lane group across 32 regs
#pragma unroll
      for (int rr = 0; rr < 4; ++rr) {
        float mx = -3.0e38f;
#pragma unroll
        for (int t = 0; t < 32; ++t) mx = fmaxf(mx, sim[t][rr]);
#pragma unroll
        for (int o = 1; o < 16; o <<= 1) mx = fmaxf(mx, __shfl_xor(mx, o));
        float s = 0.f;
#pragma unroll
        for (int t = 0; t < 32; ++t) {
          float e = __expf(sim[t][rr] - mx);
          sim[t][rr] = e;
          s += e;
        }
#pragma unroll
        for (int o = 1; o < 16; o <<= 1) s += __shfl_xor(s, o);
        float inv = 1.f / s;
#pragma unroll
        for (int t = 0; t < 32; ++t) sim[t][rr] *= inv;
      }
    }
    const unsigned short* buf = kvbuf[vt & 1];
#pragma unroll
    for (int cc = 0; cc < 4; ++cc) {
#pragma unroll
      for (int p = 0; p < 2; ++p)
#pragma unroll
        for (int rr = 0; rr < 4; ++rr)
          Ps[wave][4 * g + rr][p * 16 + l15] = f2b(sim[vt * 8 + cc * 2 + p][rr]);
      asm volatile("s_waitcnt lgkmcnt(0)" ::: "memory");
      bf16x8 pf = *(const bf16x8*)(&Ps[wave][l15][g * 8]);
#pragma unroll
      for (int m = 0; m < 4; ++m) {
        int vrow = m * 16 + l15;
        bf16x8 vf = *(const bf16x8*)(buf + (vrow * 16 + ((cc * 4 + g) ^ l15)) * 8);
        oacc[m] = mfma16(vf, pf, oacc[m]);
      }
    }
  }

  // store: ao[bm*512 + q][h*64 + d], d = m*16 + 4g + rr (4 bf16 packed)
  const int hh = bh & 7, bm = bh >> 3;
  unsigned short* aorow = ao + ((size_t)bm * 512 + qrow0 + l15) * 512 + hh * 64;
#pragma unroll
  for (int m = 0; m < 4; ++m) {
    us4 v;
#pragma unroll
    for (int rr = 0; rr < 4; ++rr) v[rr] = f2b(oacc[m][rr]);
    *(us4*)(aorow + m * 16 + 4 * g) = v;
  }
}

// ---------------------------------------------------------------------------
extern "C" void kernel_launch(void* const* d_in, const int* in_sizes, int n_in,
                              void* d_out, int out_size, void* d_ws, size_t ws_size,
                              hipStream_t stream) {
  const float* x = (const float*)d_in[0];
  // d_in[1] = pos_bias: mathematically a no-op (constant along softmax axis)
  const float* w_qkv = (const float*)d_in[2];
  const float* w_out = (const float*)d_in[3];
  float* out = (float*)d_out;

  char* ws = (char*)d_ws;
  const size_t SZ_XB = 16384ull * 512 * 2;        // 16.78 MB
  const size_t SZ_WQ = 1536ull * 512 * 2;         // 1.57 MB
  const size_t SZ_WO = 512ull * 512 * 2;          // 0.52 MB
  const size_t SZ_HB = 256ull * 512 * 64 * 2;     // 16.78 MB each
  unsigned short* xb = (unsigned short*)(ws);
  unsigned short* wqbT = (unsigned short*)(ws + SZ_XB);
  unsigned short* wobT = (unsigned short*)(ws + SZ_XB + SZ_WQ);
  unsigned short* qb = (unsigned short*)(ws + SZ_XB + SZ_WQ + SZ_WO);
  unsigned short* kb = (unsigned short*)(ws + SZ_XB + SZ_WQ + SZ_WO + SZ_HB);
  unsigned short* vtb = (unsigned short*)(ws + SZ_XB + SZ_WQ + SZ_WO + 2 * SZ_HB);
  unsigned short* ao = (unsigned short*)(ws + SZ_XB + SZ_WQ + SZ_WO + 3 * SZ_HB);

  cast_x_kernel<<<8192, 256, 0, stream>>>(x, xb);
  transpose_cast_kernel<<<dim3(1536 / 64, 512 / 64), 256, 0, stream>>>(w_qkv, wqbT, 512, 1536);
  transpose_cast_kernel<<<dim3(512 / 64, 512 / 64), 256, 0, stream>>>(w_out, wobT, 512, 512);
  gemm_qkv_kernel<<<dim3(128, 12), 256, 0, stream>>>(xb, wqbT, qb, kb, vtb);
  attn_kernel<<<dim3(256, 8), 256, 0, stream>>>(qb, kb, vtb, ao);
  gemm_out_kernel<<<dim3(128, 4), 256, 0, stream>>>(ao, wobT, out);
}

// Round 3
// 117.716 us; speedup vs baseline: 1.7603x; 1.1104x over previous
//
#include <hip/hip_runtime.h>
#include <stdint.h>

// ---------------------------------------------------------------------------
// Attention_59236188947093: x[4,8,512,512] -> qkv proj -> 8-head attn (n=512,
// d=64) -> out proj. pos_bias is a softmax-axis constant => mathematically
// irrelevant, skipped. All matmuls in bf16 MFMA (16x16x32), fp32 accum.
// ---------------------------------------------------------------------------

typedef __attribute__((ext_vector_type(8))) short bf16x8;
typedef __attribute__((ext_vector_type(4))) float f32x4;
typedef __attribute__((ext_vector_type(4))) unsigned short us4;
typedef __attribute__((ext_vector_type(4))) float float4v;

__device__ __forceinline__ unsigned short f2b(float f) {
  union { float f; uint32_t u; } x; x.f = f;
  uint32_t r = x.u + 0x7fffu + ((x.u >> 16) & 1u);
  return (unsigned short)(r >> 16);
}

__device__ __forceinline__ f32x4 mfma16(bf16x8 a, bf16x8 b, f32x4 c) {
  return __builtin_amdgcn_mfma_f32_16x16x32_bf16(a, b, c, 0, 0, 0);
}

__device__ __forceinline__ void gload_lds16(const unsigned short* g, unsigned short* l) {
  __builtin_amdgcn_global_load_lds(
      (const __attribute__((address_space(1))) unsigned int*)g,
      (__attribute__((address_space(3))) unsigned int*)l, 16, 0, 0);
}

// ---------------------------------------------------------------------------
// cast kernels
// ---------------------------------------------------------------------------
__global__ __launch_bounds__(256) void cast_x_kernel(
    const float* __restrict__ src, unsigned short* __restrict__ dst) {
  size_t i = ((size_t)blockIdx.x * 256 + threadIdx.x) * 4;
  float4v v = *(const float4v*)(src + i);
  us4 o;
#pragma unroll
  for (int j = 0; j < 4; ++j) o[j] = f2b(v[j]);
  *(us4*)(dst + i) = o;
}

// src[R][C] fp32 -> dst[C][R] bf16
__global__ __launch_bounds__(256) void transpose_cast_kernel(
    const float* __restrict__ src, unsigned short* __restrict__ dst, int R, int C) {
  __shared__ float tile[64][65];
  const int tc0 = blockIdx.x * 64;
  const int tr0 = blockIdx.y * 64;
#pragma unroll
  for (int k2 = 0; k2 < 16; ++k2) {
    int idx = threadIdx.x + k2 * 256;
    int r = idx >> 6, c = idx & 63;
    tile[r][c] = src[(size_t)(tr0 + r) * C + tc0 + c];
  }
  __syncthreads();
#pragma unroll
  for (int k2 = 0; k2 < 16; ++k2) {
    int idx = threadIdx.x + k2 * 256;
    int c = idx >> 6, r = idx & 63;
    dst[(size_t)(tc0 + c) * R + tr0 + r] = f2b(tile[r][c]);
  }
}

// ---------------------------------------------------------------------------
// GEMM core: C[128x128] tile of A[M][K] * Bt[N][K]^T, K multiple of 64.
// 4 waves in 2x2, each wave 64x64 via 4x4 frags of 16x16x32 bf16 MFMA.
// LDS tiles are [128 rows][8 chunks of 16B] with chunk index XOR-swizzled by
// row&7 (T2): swizzle applied to the GLOBAL source of global_load_lds (dest
// must stay linear) and to the ds_read_b128 address -> 16-way conflict -> 2-way.
// ---------------------------------------------------------------------------
__device__ __forceinline__ void gemm_core(
    const unsigned short* __restrict__ A, const unsigned short* __restrict__ Bt,
    int K, int r0, int c0, unsigned short* As, unsigned short* Bs,
    f32x4 (&acc)[4][4]) {
  const int tid = threadIdx.x;
  const int lane = tid & 63;
  const int wave = tid >> 6;
  const int wr = (wave >> 1) * 64;
  const int wc = (wave & 1) * 64;
  const int l15 = lane & 15;
  const int g = lane >> 4;
  const int lsw = l15 & 7;

#pragma unroll
  for (int m = 0; m < 4; ++m)
#pragma unroll
    for (int n = 0; n < 4; ++n) acc[m][n] = (f32x4){0.f, 0.f, 0.f, 0.f};

  for (int kt = 0; kt < K; kt += 64) {
#pragma unroll
    for (int i = 0; i < 4; ++i) {
      int chunk = tid + i * 256;        // 1024 chunks of 16B per 128x64 tile
      int row = chunk >> 3;
      int csw = (chunk & 7) ^ (row & 7);  // pre-swizzled global chunk
      gload_lds16(A + (size_t)(r0 + row) * K + kt + csw * 8, As + chunk * 8);
      gload_lds16(Bt + (size_t)(c0 + row) * K + kt + csw * 8, Bs + chunk * 8);
    }
    __syncthreads();
#pragma unroll
    for (int ks = 0; ks < 2; ++ks) {
      bf16x8 af[4], bfr[4];
      const int j = g + ks * 4;
      const int cj = (j ^ lsw) * 8;
#pragma unroll
      for (int m = 0; m < 4; ++m)
        af[m] = *(const bf16x8*)(As + (wr + m * 16 + l15) * 64 + cj);
#pragma unroll
      for (int n = 0; n < 4; ++n)
        bfr[n] = *(const bf16x8*)(Bs + (wc + n * 16 + l15) * 64 + cj);
#pragma unroll
      for (int m = 0; m < 4; ++m)
#pragma unroll
        for (int n = 0; n < 4; ++n) acc[m][n] = mfma16(af[m], bfr[n], acc[m][n]);
    }
    __syncthreads();
  }
}

// ---------------------------------------------------------------------------
// QKV projection: xb[16384][512] * wqbT[1536][512]^T -> q/k/vt bf16 via
// LDS-transposed epilogue (coalesced 16B stores).
// q,k: [bh=256][n=512][d=64]; vt: [bh][d=64][n=512]. q scaled by d^-0.5.
// ---------------------------------------------------------------------------
__global__ __launch_bounds__(256) void gemm_qkv_kernel(
    const unsigned short* __restrict__ xb, const unsigned short* __restrict__ wqbT,
    unsigned short* __restrict__ qb, unsigned short* __restrict__ kb,
    unsigned short* __restrict__ vtb) {
  __shared__ unsigned short smem[16384];
  f32x4 acc[4][4];
  const int r0 = blockIdx.x * 128;
  const int c0 = blockIdx.y * 128;
  gemm_core(xb, wqbT, 512, r0, c0, smem, smem + 8192, acc);
  // gemm_core ends with __syncthreads(); smem is free for epilogue reuse

  const int tid = threadIdx.x, lane = tid & 63, wave = tid >> 6;
  const int wr = (wave >> 1) * 64, wc = (wave & 1) * 64;
  const int l15 = lane & 15, g = lane >> 4;
  const int part = c0 >> 9;  // 128-wide tile lies in exactly one of q/k/v
  const float scl = (part == 0) ? 0.125f : 1.0f;

  if (part < 2) {
    // stage C[row][col] bf16, 16B-chunk index XOR row&15
#pragma unroll
    for (int m = 0; m < 4; ++m) {
      int rbase = wr + m * 16 + 4 * g;
#pragma unroll
      for (int n = 0; n < 4; ++n) {
        int c = wc + n * 16 + l15;
        int c2 = c >> 3, ci = c & 7;
#pragma unroll
        for (int rr = 0; rr < 4; ++rr) {
          int r = rbase + rr;
          smem[r * 128 + ((c2 ^ (r & 15)) << 3) + ci] = f2b(acc[m][n][rr] * scl);
        }
      }
    }
    __syncthreads();
    unsigned short* dstb = (part == 0) ? qb : kb;
#pragma unroll
    for (int it = 0; it < 8; ++it) {
      int idx = tid + it * 256;
      int r = idx >> 4, c2 = idx & 15;
      bf16x8 v = *(const bf16x8*)(smem + r * 128 + ((c2 ^ (r & 15)) << 3));
      int e = c0 + c2 * 8;
      int rem = e & 511, h = rem >> 6, d = rem & 63;
      int ig = r0 + r;
      int bh = (ig >> 9) * 8 + h, i = ig & 511;
      *(bf16x8*)(dstb + ((size_t)bh * 512 + i) * 64 + d) = v;
    }
  } else {
    // transposed staging T[col][row], 16B-chunk (8 rows) index XOR col&15
#pragma unroll
    for (int m = 0; m < 4; ++m) {
      int rbase = wr + m * 16 + 4 * g;        // multiple of 4
      int r2 = rbase >> 3, rhalf = rbase & 7; // rhalf in {0,4}
#pragma unroll
      for (int n = 0; n < 4; ++n) {
        int c = wc + n * 16 + l15;
        us4 v;
#pragma unroll
        for (int rr = 0; rr < 4; ++rr) v[rr] = f2b(acc[m][n][rr]);
        *(us4*)(smem + c * 128 + ((r2 ^ (c & 15)) << 3) + rhalf) = v;
      }
    }
    __syncthreads();
#pragma unroll
    for (int it = 0; it < 8; ++it) {
      int idx = tid + it * 256;
      int c = idx >> 4, r8 = idx & 15;
      bf16x8 v = *(const bf16x8*)(smem + c * 128 + ((r8 ^ (c & 15)) << 3));
      int e = c0 + c;
      int rem = e & 511, h = rem >> 6, d = rem & 63;
      int ig0 = r0 + r8 * 8;
      int bh = (ig0 >> 9) * 8 + h, i = ig0 & 511;
      *(bf16x8*)(vtb + ((size_t)bh * 64 + d) * 512 + i) = v;
    }
  }
}

// ---------------------------------------------------------------------------
// Output projection: ao[16384][512] * wobT[512][512]^T -> d_out fp32
// ---------------------------------------------------------------------------
__global__ __launch_bounds__(256) void gemm_out_kernel(
    const unsigned short* __restrict__ ao, const unsigned short* __restrict__ wobT,
    float* __restrict__ out) {
  __shared__ unsigned short smem[16384];
  f32x4 acc[4][4];
  const int r0 = blockIdx.x * 128;
  const int c0 = blockIdx.y * 128;
  gemm_core(ao, wobT, 512, r0, c0, smem, smem + 8192, acc);

  const int tid = threadIdx.x, lane = tid & 63, wave = tid >> 6;
  const int wr = (wave >> 1) * 64, wc = (wave & 1) * 64;
  const int l15 = lane & 15, g = lane >> 4;
#pragma unroll
  for (int m = 0; m < 4; ++m) {
    int i0g = r0 + wr + m * 16 + 4 * g;
#pragma unroll
    for (int n = 0; n < 4; ++n) {
      int e = c0 + wc + n * 16 + l15;
#pragma unroll
      for (int rr = 0; rr < 4; ++rr)
        out[(size_t)(i0g + rr) * 512 + e] = acc[m][n][rr];
    }
  }
}

// ---------------------------------------------------------------------------
// Fused attention v2: block = (bh, 64 q-rows), 4 waves x 16 q-rows.
// K and V^T staged through double-buffered 16KB LDS tiles via global_load_lds
// with XOR-swizzled GLOBAL source (LDS dest must stay linear), so ds_read_b128
// fragment reads are bank-balanced. sim (16x512 fp32) fully in registers.
// Pipeline: [syncthreads (drains vmcnt) | issue next tile | compute this tile].
// ---------------------------------------------------------------------------
__global__ __launch_bounds__(256, 2) void attn_kernel(
    const unsigned short* __restrict__ qb, const unsigned short* __restrict__ kb,
    const unsigned short* __restrict__ vtb, unsigned short* __restrict__ ao) {
  __shared__ unsigned short kvbuf[2][8192];   // 2 x 16KB
  __shared__ unsigned short Ps[4][16][40];
  const int bh = blockIdx.x;   // x = bh so all 8 q-tiles of a bh land on one XCD stream
  const int qt = blockIdx.y;
  const int tid = threadIdx.x, lane = tid & 63, wave = tid >> 6;
  const int l15 = lane & 15, g = lane >> 4;
  const int qrow0 = qt * 64 + wave * 16;

  const unsigned short* Q = qb + ((size_t)bh * 512 + qrow0) * 64;
  const unsigned short* Kp = kb + (size_t)bh * 512 * 64;
  const unsigned short* Vt = vtb + (size_t)bh * 64 * 512;

  bf16x8 qf0 = *(const bf16x8*)(Q + l15 * 64 + g * 8);
  bf16x8 qf1 = *(const bf16x8*)(Q + l15 * 64 + 32 + g * 8);

  // staging geometry (per thread, constant across the 4 chunks it loads)
  const int krow_b = tid >> 3;                    // K: base row, +32 per i
  const int kck = (tid & 7) ^ (krow_b & 7);       // K: swizzled global chunk
  const int vrow_b = tid >> 4;                    // V: base row (d), +16 per i
  const int vck = (tid & 15) ^ (vrow_b & 15);     // V: swizzled global chunk

  f32x4 sim[32];
#pragma unroll
  for (int t = 0; t < 32; ++t) sim[t] = (f32x4){0.f, 0.f, 0.f, 0.f};

  // prologue: stage K tile 0 into buf 0
#pragma unroll
  for (int i = 0; i < 4; ++i)
    gload_lds16(Kp + (size_t)(krow_b + i * 32) * 64 + kck * 8,
                kvbuf[0] + tid * 8 + i * 2048);

  // ---- K phases: QK^T ----
#pragma unroll
  for (int kt = 0; kt < 4; ++kt) {
    __syncthreads();  // implicit vmcnt(0): tile kt landed; prev buffer free
    if (kt < 3) {
#pragma unroll
      for (int i = 0; i < 4; ++i)
        gload_lds16(Kp + (size_t)((kt + 1) * 128 + krow_b + i * 32) * 64 + kck * 8,
                    kvbuf[(kt + 1) & 1] + tid * 8 + i * 2048);
    } else {
#pragma unroll
      for (int i = 0; i < 4; ++i)
        gload_lds16(Vt + (size_t)(vrow_b + i * 16) * 512 + vck * 8,
                    kvbuf[0] + tid * 8 + i * 2048);
    }
    const unsigned short* buf = kvbuf[kt & 1];
#pragma unroll
    for (int tt = 0; tt < 8; ++tt) {
      int row = tt * 16 + l15;
      int c0 = g ^ (l15 & 7);
      bf16x8 b0 = *(const bf16x8*)(buf + (row * 8 + c0) * 8);
      bf16x8 b1 = *(const bf16x8*)(buf + (row * 8 + (c0 ^ 4)) * 8);
      sim[kt * 8 + tt] = mfma16(qf0, b0, sim[kt * 8 + tt]);
      sim[kt * 8 + tt] = mfma16(qf1, b1, sim[kt * 8 + tt]);
    }
  }

  f32x4 oacc[4];
#pragma unroll
  for (int m = 0; m < 4; ++m) oacc[m] = (f32x4){0.f, 0.f, 0.f, 0.f};

  // ---- V phases: softmax (vt==0) + PV ----
#pragma unroll
  for (int vt = 0; vt < 4; ++vt) {
    __syncthreads();  // V tile vt landed
    if (vt < 3) {
#pragma unroll
      for (int i = 0; i < 4; ++i)
        gload_lds16(Vt + (size_t)(vrow_b + i * 16) * 512 + (vt + 1) * 128 + vck * 8,
                    kvbuf[(vt + 1) & 1] + tid * 8 + i * 2048);
    }
    if (vt == 0) {
      // softmax: row (4g+rr) lives in one 16-lane group across 32 regs
#pragma unroll
      for (int rr = 0; rr < 4; ++rr) {
        float mx = -3.0e38f;
#pragma unroll
        for (int t = 0; t < 32; ++t) mx = fmaxf(mx, sim[t][rr]);
#pragma unroll
        for (int o = 1; o < 16; o <<= 1) mx = fmaxf(mx, __shfl_xor(mx, o));
        float s = 0.f;
#pragma unroll
        for (int t = 0; t < 32; ++t) {
          float e = __expf(sim[t][rr] - mx);
          sim[t][rr] = e;
          s += e;
        }
#pragma unroll
        for (int o = 1; o < 16; o <<= 1) s += __shfl_xor(s, o);
        float inv = 1.f / s;
#pragma unroll
        for (int t = 0; t < 32; ++t) sim[t][rr] *= inv;
      }
    }
    const unsigned short* buf = kvbuf[vt & 1];
#pragma unroll
    for (int cc = 0; cc < 4; ++cc) {
#pragma unroll
      for (int p = 0; p < 2; ++p)
#pragma unroll
        for (int rr = 0; rr < 4; ++rr)
          Ps[wave][4 * g + rr][p * 16 + l15] = f2b(sim[vt * 8 + cc * 2 + p][rr]);
      asm volatile("s_waitcnt lgkmcnt(0)" ::: "memory");
      bf16x8 pf = *(const bf16x8*)(&Ps[wave][l15][g * 8]);
#pragma unroll
      for (int m = 0; m < 4; ++m) {
        int vrow = m * 16 + l15;
        bf16x8 vf = *(const bf16x8*)(buf + (vrow * 16 + ((cc * 4 + g) ^ l15)) * 8);
        oacc[m] = mfma16(vf, pf, oacc[m]);
      }
    }
  }

  // store: ao[bm*512 + q][h*64 + d], d = m*16 + 4g + rr (4 bf16 packed)
  const int hh = bh & 7, bm = bh >> 3;
  unsigned short* aorow = ao + ((size_t)bm * 512 + qrow0 + l15) * 512 + hh * 64;
#pragma unroll
  for (int m = 0; m < 4; ++m) {
    us4 v;
#pragma unroll
    for (int rr = 0; rr < 4; ++rr) v[rr] = f2b(oacc[m][rr]);
    *(us4*)(aorow + m * 16 + 4 * g) = v;
  }
}

// ---------------------------------------------------------------------------
extern "C" void kernel_launch(void* const* d_in, const int* in_sizes, int n_in,
                              void* d_out, int out_size, void* d_ws, size_t ws_size,
                              hipStream_t stream) {
  const float* x = (const float*)d_in[0];
  // d_in[1] = pos_bias: mathematically a no-op (constant along softmax axis)
  const float* w_qkv = (const float*)d_in[2];
  const float* w_out = (const float*)d_in[3];
  float* out = (float*)d_out;

  char* ws = (char*)d_ws;
  const size_t SZ_XB = 16384ull * 512 * 2;        // 16.78 MB
  const size_t SZ_WQ = 1536ull * 512 * 2;         // 1.57 MB
  const size_t SZ_WO = 512ull * 512 * 2;          // 0.52 MB
  const size_t SZ_HB = 256ull * 512 * 64 * 2;     // 16.78 MB each
  unsigned short* xb = (unsigned short*)(ws);
  unsigned short* wqbT = (unsigned short*)(ws + SZ_XB);
  unsigned short* wobT = (unsigned short*)(ws + SZ_XB + SZ_WQ);
  unsigned short* qb = (unsigned short*)(ws + SZ_XB + SZ_WQ + SZ_WO);
  unsigned short* kb = (unsigned short*)(ws + SZ_XB + SZ_WQ + SZ_WO + SZ_HB);
  unsigned short* vtb = (unsigned short*)(ws + SZ_XB + SZ_WQ + SZ_WO + 2 * SZ_HB);
  unsigned short* ao = (unsigned short*)(ws + SZ_XB + SZ_WQ + SZ_WO + 3 * SZ_HB);

  cast_x_kernel<<<8192, 256, 0, stream>>>(x, xb);
  transpose_cast_kernel<<<dim3(1536 / 64, 512 / 64), 256, 0, stream>>>(w_qkv, wqbT, 512, 1536);
  transpose_cast_kernel<<<dim3(512 / 64, 512 / 64), 256, 0, stream>>>(w_out, wobT, 512, 512);
  gemm_qkv_kernel<<<dim3(128, 12), 256, 0, stream>>>(xb, wqbT, qb, kb, vtb);
  attn_kernel<<<dim3(256, 8), 256, 0, stream>>>(qb, kb, vtb, ao);
  gemm_out_kernel<<<dim3(128, 4), 256, 0, stream>>>(ao, wobT, out);
}